// Round 4
// baseline (140.983 us; speedup 1.0000x reference)
//
#include <hip/hip_runtime.h>

#define NDOF 7
#define BLK 256
#define CST_STRIDE 24               // floats per dof block
#define CST_TOT (NDOF * CST_STRIDE) // 168
#define BELEM (BLK * NDOF)          // 1792 floats staged per array per block
#define BVEC (BELEM / 4)            // 448 float4

// ---------- tiny vec3 ----------
struct V3 { float x, y, z; };
__device__ __forceinline__ V3 operator+(V3 a, V3 b) { return {a.x + b.x, a.y + b.y, a.z + b.z}; }
__device__ __forceinline__ V3 operator-(V3 a, V3 b) { return {a.x - b.x, a.y - b.y, a.z - b.z}; }
__device__ __forceinline__ V3 operator*(float s, V3 a) { return {s * a.x, s * a.y, s * a.z}; }
__device__ __forceinline__ V3 cross(V3 a, V3 b) {
    return {a.y * b.z - a.z * b.y, a.z * b.x - a.x * b.z, a.x * b.y - a.y * b.x};
}
__device__ __forceinline__ float dot(V3 a, V3 b) { return a.x * b.x + a.y * b.y + a.z * b.z; }

// ---------- prep: pack per-dof constants into d_ws ----------
// per dof d (24 floats): [0:9) F columns (column-major), [9:12) p,
// [12:18) Io6=I00,I01,I02,I11,I12,I22, [18] m, [19:22) mc, [22] damp, [23] pad
__global__ void rnea_prep(const float* __restrict__ rot_fix,
                          const float* __restrict__ trans_fix,
                          const float* __restrict__ mass_g,
                          const float* __restrict__ com_g,
                          const float* __restrict__ inertia_g,
                          const float* __restrict__ damping_g,
                          float* __restrict__ cst) {
    const int d = threadIdx.x;
    if (d >= NDOF) return;
    float* o = cst + d * CST_STRIDE;
    const float* F = rot_fix + (1 + d) * 9;
#pragma unroll
    for (int j = 0; j < 3; j++)
#pragma unroll
        for (int i = 0; i < 3; i++) o[j * 3 + i] = F[i * 3 + j];  // column-major
#pragma unroll
    for (int i = 0; i < 3; i++) o[9 + i] = trans_fix[(1 + d) * 3 + i];
    const float m = mass_g[1 + d];
    const float c0 = com_g[(1 + d) * 3 + 0];
    const float c1 = com_g[(1 + d) * 3 + 1];
    const float c2 = com_g[(1 + d) * 3 + 2];
    const float* I = inertia_g + (1 + d) * 9;
    o[12] = I[0] + m * (c1 * c1 + c2 * c2);
    o[13] = I[1] - m * c0 * c1;
    o[14] = I[2] - m * c0 * c2;
    o[15] = I[4] + m * (c0 * c0 + c2 * c2);
    o[16] = I[5] - m * c1 * c2;
    o[17] = I[8] + m * (c0 * c0 + c1 * c1);
    o[18] = m;
    o[19] = m * c0;
    o[20] = m * c1;
    o[21] = m * c2;
    o[22] = damping_g[d];
    o[23] = 0.f;
}

// AX: 0 = +z, 1 = +y, 2 = -y   (joint_axes is a literal in the reference)
template <int AX>
__device__ __forceinline__ void make_R(V3 Fc0, V3 Fc1, V3 Fc2, float s, float c,
                                       V3& R0, V3& R1, V3& R2) {
    if (AX == 0) {          // Rq_z cols: (c,s,0), (-s,c,0), (0,0,1)
        R0 = c * Fc0 + s * Fc1;
        R1 = c * Fc1 - s * Fc0;
        R2 = Fc2;
    } else if (AX == 1) {   // Rq_y cols: (c,0,-s), (0,1,0), (s,0,c)
        R0 = c * Fc0 - s * Fc2;
        R1 = Fc1;
        R2 = s * Fc0 + c * Fc2;
    } else {                // Rq_-y cols: (c,0,s), (0,1,0), (-s,0,c)
        R0 = c * Fc0 + s * Fc2;
        R1 = Fc1;
        R2 = c * Fc2 - s * Fc0;
    }
}

// fwd: computes this link's fl/fa (local frame) and updates v/a state in place.
// Constants via uniform pointer + compile-time indices -> s_load (SGPRs).
template <int AX>
__device__ __forceinline__ void fwd_step(const float* __restrict__ C, float s, float c,
                                         float qd, float qdd, V3& vl, V3& va, V3& al,
                                         V3& aa, V3& fl, V3& fa) {
    const V3 Fc0{C[0], C[1], C[2]};
    const V3 Fc1{C[3], C[4], C[5]};
    const V3 Fc2{C[6], C[7], C[8]};
    const V3 p{C[9], C[10], C[11]};
    const float I00 = C[12], I01 = C[13], I02 = C[14], I11 = C[15], I12 = C[16], I22 = C[17];
    const float m = C[18];
    const V3 mc{C[19], C[20], C[21]};

    V3 R0, R1, R2;
    make_R<AX>(Fc0, Fc1, Fc2, s, c, R0, R1, R2);

    // Rt(vl) + cross(-Rt p, Rt va) == Rt(vl + va x p)
    V3 w1 = vl + cross(va, p);
    V3 w2 = al + cross(aa, p);
    V3 nvl{dot(R0, w1), dot(R1, w1), dot(R2, w1)};
    V3 nva{dot(R0, va), dot(R1, va), dot(R2, va)};
    V3 nal{dot(R0, w2), dot(R1, w2), dot(R2, w2)};
    V3 naa{dot(R0, aa), dot(R1, aa), dot(R2, aa)};

    if (AX == 0) {          // jv=(0,0,qd): cross(v,jv)=(v.y*qd,-v.x*qd,0)
        va = {nva.x, nva.y, nva.z + qd};
        aa = {naa.x + va.y * qd, naa.y - va.x * qd, naa.z + qdd};
        vl = nvl;
        al = {nal.x + vl.y * qd, nal.y - vl.x * qd, nal.z};
    } else if (AX == 1) {   // jv=(0,qd,0): cross(v,jv)=(-v.z*qd,0,v.x*qd)
        va = {nva.x, nva.y + qd, nva.z};
        aa = {naa.x - va.z * qd, naa.y + qdd, naa.z + va.x * qd};
        vl = nvl;
        al = {nal.x - vl.z * qd, nal.y, nal.z + vl.x * qd};
    } else {                // jv=(0,-qd,0): cross(v,jv)=(v.z*qd,0,-v.x*qd)
        va = {nva.x, nva.y - qd, nva.z};
        aa = {naa.x + va.z * qd, naa.y - qdd, naa.z - va.x * qd};
        vl = nvl;
        al = {nal.x + vl.z * qd, nal.y, nal.z - vl.x * qd};
    }

    V3 Ial = m * al + cross(aa, mc);
    V3 Iaa = V3{I00 * aa.x + I01 * aa.y + I02 * aa.z,
                I01 * aa.x + I11 * aa.y + I12 * aa.z,
                I02 * aa.x + I12 * aa.y + I22 * aa.z} + cross(mc, al);
    V3 Ivl = m * vl + cross(va, mc);
    V3 Iva = V3{I00 * va.x + I01 * va.y + I02 * va.z,
                I01 * va.x + I11 * va.y + I12 * va.z,
                I02 * va.x + I12 * va.y + I22 * va.z} + cross(mc, vl);
    fl = Ial + cross(va, Ivl);
    fa = Iaa + cross(va, Iva) + cross(vl, Ivl);
}

// bwd: consumes fl/fa by value (register-parked), updates carry, returns tau.
template <int AX>
__device__ __forceinline__ float bwd_core(const float* __restrict__ C, float s, float c,
                                          V3 fl, V3 fa, V3& cl, V3& ca) {
    const V3 Fc0{C[0], C[1], C[2]};
    const V3 Fc1{C[3], C[4], C[5]};
    const V3 Fc2{C[6], C[7], C[8]};
    const V3 p{C[9], C[10], C[11]};

    V3 tl = fl + cl;
    V3 ta = fa + ca;
    float tau;
    if (AX == 0) tau = ta.z;
    else if (AX == 1) tau = ta.y;
    else tau = -ta.y;

    V3 R0, R1, R2;
    make_R<AX>(Fc0, Fc1, Fc2, s, c, R0, R1, R2);
    V3 nl = tl.x * R0 + tl.y * R1 + tl.z * R2;   // R @ tl (columns)
    V3 na = ta.x * R0 + ta.y * R1 + ta.z * R2 + cross(p, nl);
    cl = nl;
    ca = na;
    return tau;
}

// ---------- main kernel ----------
// O(n) two-pass RNEA in registers (r2 body) + COALESCED staged I/O.
// Round-3 diagnosis: VALUBusy pinned at 49% with dur*VALUBusy == const across
// variants and no response to added ILP -> the other ~51% is vector-memory
// address-divergence serialization in the per-CU TA: [row][7] layout gives
// 28 B lane stride, so each wave64 load/store splits into ~28 segments
// (~780 TA cycles/wave for 21 loads + 7 stores vs ~3000 VALU cycles).
// Fix: each block's 256 rows span a CONTIGUOUS 7168 B region per array ->
// cooperative float4 loads into LDS (16 segs/instr, ~84 TA cyc/wave total),
// per-thread LDS reads at stride 7 (coprime 32 banks = conflict-free),
// and the same staging in reverse for the output store.
__global__ __launch_bounds__(BLK) void rnea_main(
    const float* __restrict__ q_g, const float* __restrict__ qd_g,
    const float* __restrict__ qdd_g, const float* __restrict__ cst,
    float* __restrict__ out, int nbatch) {
    __shared__ __align__(16) float sQ[BELEM];
    __shared__ __align__(16) float sQd[BELEM];
    __shared__ __align__(16) float sQdd[BELEM];
    const int t = threadIdx.x;
    const int row0 = blockIdx.x * BLK;
    const size_t base = (size_t)row0 * NDOF;          // float offset; base*4 % 16 == 0
    const bool full = (row0 + BLK) <= nbatch;

    if (full) {
        const float4* gq = reinterpret_cast<const float4*>(q_g + base);
        const float4* gqd = reinterpret_cast<const float4*>(qd_g + base);
        const float4* gqdd = reinterpret_cast<const float4*>(qdd_g + base);
        float4* s4q = reinterpret_cast<float4*>(sQ);
        float4* s4qd = reinterpret_cast<float4*>(sQd);
        float4* s4qdd = reinterpret_cast<float4*>(sQdd);
#pragma unroll
        for (int i = 0; i < 2; i++) {
            const int idx = t + i * BLK;
            if (idx < BVEC) {
                s4q[idx] = gq[idx];
                s4qd[idx] = gqd[idx];
                s4qdd[idx] = gqdd[idx];
            }
        }
    } else {
        const int totalE = nbatch * NDOF;
        for (int i = t; i < BELEM; i += BLK) {
            const size_t gi = base + i;
            const bool in = gi < (size_t)totalE;
            sQ[i] = in ? q_g[gi] : 0.f;
            sQd[i] = in ? qd_g[gi] : 0.f;
            sQdd[i] = in ? qdd_g[gi] : 0.f;
        }
    }
    __syncthreads();

    float qd[NDOF], qdd[NDOF], ss[NDOF], cc[NDOF];
#pragma unroll
    for (int d = 0; d < NDOF; d++) {
        const float qv = sQ[t * NDOF + d];
        ss[d] = __sinf(qv);
        cc[d] = __cosf(qv);
        qd[d] = sQd[t * NDOF + d];
        qdd[d] = sQdd[t * NDOF + d];
    }

    V3 vl{0.f, 0.f, 0.f}, va{0.f, 0.f, 0.f}, al{0.f, 0.f, 9.81f}, aa{0.f, 0.f, 0.f};
    V3 fl0, fa0, fl1, fa1, fl2, fa2, fl3, fa3, fl4, fa4, fl5, fa5, fl6, fa6;

    // axis sequence: z, y, z, -y, z, y, z -> AX ids 0,1,0,2,0,1,0
    fwd_step<0>(cst + 0 * CST_STRIDE, ss[0], cc[0], qd[0], qdd[0], vl, va, al, aa, fl0, fa0);
    fwd_step<1>(cst + 1 * CST_STRIDE, ss[1], cc[1], qd[1], qdd[1], vl, va, al, aa, fl1, fa1);
    fwd_step<0>(cst + 2 * CST_STRIDE, ss[2], cc[2], qd[2], qdd[2], vl, va, al, aa, fl2, fa2);
    fwd_step<2>(cst + 3 * CST_STRIDE, ss[3], cc[3], qd[3], qdd[3], vl, va, al, aa, fl3, fa3);
    fwd_step<0>(cst + 4 * CST_STRIDE, ss[4], cc[4], qd[4], qdd[4], vl, va, al, aa, fl4, fa4);
    fwd_step<1>(cst + 5 * CST_STRIDE, ss[5], cc[5], qd[5], qdd[5], vl, va, al, aa, fl5, fa5);
    fwd_step<0>(cst + 6 * CST_STRIDE, ss[6], cc[6], qd[6], qdd[6], vl, va, al, aa, fl6, fa6);

    V3 cl{0.f, 0.f, 0.f}, ca{0.f, 0.f, 0.f};
    float tau[NDOF];
    tau[6] = bwd_core<0>(cst + 6 * CST_STRIDE, ss[6], cc[6], fl6, fa6, cl, ca);
    tau[5] = bwd_core<1>(cst + 5 * CST_STRIDE, ss[5], cc[5], fl5, fa5, cl, ca);
    tau[4] = bwd_core<0>(cst + 4 * CST_STRIDE, ss[4], cc[4], fl4, fa4, cl, ca);
    tau[3] = bwd_core<2>(cst + 3 * CST_STRIDE, ss[3], cc[3], fl3, fa3, cl, ca);
    tau[2] = bwd_core<0>(cst + 2 * CST_STRIDE, ss[2], cc[2], fl2, fa2, cl, ca);
    tau[1] = bwd_core<1>(cst + 1 * CST_STRIDE, ss[1], cc[1], fl1, fa1, cl, ca);
    tau[0] = bwd_core<0>(cst + 0 * CST_STRIDE, ss[0], cc[0], fl0, fa0, cl, ca);

    // all threads are past their sQ reads (program order); reuse sQ for output
    __syncthreads();
#pragma unroll
    for (int d = 0; d < NDOF; d++)
        sQ[t * NDOF + d] = tau[d] + cst[d * CST_STRIDE + 22] * qd[d];
    __syncthreads();

    if (full) {
        const float4* s4 = reinterpret_cast<const float4*>(sQ);
        float4* g4 = reinterpret_cast<float4*>(out + base);
#pragma unroll
        for (int i = 0; i < 2; i++) {
            const int idx = t + i * BLK;
            if (idx < BVEC) g4[idx] = s4[idx];
        }
    } else {
        const int totalE = nbatch * NDOF;
        for (int i = t; i < BELEM; i += BLK) {
            const size_t gi = base + i;
            if (gi < (size_t)totalE) out[gi] = sQ[i];
        }
    }
}

extern "C" void kernel_launch(void* const* d_in, const int* in_sizes, int n_in,
                              void* d_out, int out_size, void* d_ws, size_t ws_size,
                              hipStream_t stream) {
    const float* q = (const float*)d_in[0];
    const float* qd = (const float*)d_in[1];
    const float* qdd = (const float*)d_in[2];
    const float* rot_fix = (const float*)d_in[3];
    const float* trans_fix = (const float*)d_in[4];
    // d_in[5] = joint_axes: compile-time constant in the reference (z,y,z,-y,z,y,z)
    const float* mass = (const float*)d_in[6];
    const float* com = (const float*)d_in[7];
    const float* inertia = (const float*)d_in[8];
    const float* damping = (const float*)d_in[9];
    float* out = (float*)d_out;
    float* cst = (float*)d_ws;  // 7*24*4 = 672 B

    const int n_elem = in_sizes[0];  // B * 7
    const int B = n_elem / NDOF;
    const int grid = (B + BLK - 1) / BLK;

    rnea_prep<<<1, 64, 0, stream>>>(rot_fix, trans_fix, mass, com, inertia, damping, cst);
    rnea_main<<<grid, BLK, 0, stream>>>(q, qd, qdd, cst, out, B);
}

// Round 5
// 126.770 us; speedup vs baseline: 1.1121x; 1.1121x over previous
//
#include <hip/hip_runtime.h>

#define NDOF 7
#define BLK 256
#define CST_STRIDE 24               // floats per dof block (= 6 float4)
#define CST_TOT (NDOF * CST_STRIDE) // 168
#define SF_FLOATS (NDOF * 6 * BLK)  // 10752 floats = 43008 B parked wrenches

// ---------- tiny vec3 ----------
struct V3 { float x, y, z; };
__device__ __forceinline__ V3 operator+(V3 a, V3 b) { return {a.x + b.x, a.y + b.y, a.z + b.z}; }
__device__ __forceinline__ V3 operator-(V3 a, V3 b) { return {a.x - b.x, a.y - b.y, a.z - b.z}; }
__device__ __forceinline__ V3 operator*(float s, V3 a) { return {s * a.x, s * a.y, s * a.z}; }
__device__ __forceinline__ V3 cross(V3 a, V3 b) {
    return {a.y * b.z - a.z * b.y, a.z * b.x - a.x * b.z, a.x * b.y - a.y * b.x};
}
__device__ __forceinline__ float dot(V3 a, V3 b) { return a.x * b.x + a.y * b.y + a.z * b.z; }

// AX: 0 = +z, 1 = +y, 2 = -y   (joint_axes is a literal in the reference)
template <int AX>
__device__ __forceinline__ void make_R(V3 Fc0, V3 Fc1, V3 Fc2, float s, float c,
                                       V3& R0, V3& R1, V3& R2) {
    if (AX == 0) {          // Rq_z cols: (c,s,0), (-s,c,0), (0,0,1)
        R0 = c * Fc0 + s * Fc1;
        R1 = c * Fc1 - s * Fc0;
        R2 = Fc2;
    } else if (AX == 1) {   // Rq_y cols: (c,0,-s), (0,1,0), (s,0,c)
        R0 = c * Fc0 - s * Fc2;
        R1 = Fc1;
        R2 = s * Fc0 + c * Fc2;
    } else {                // Rq_-y cols: (c,0,s), (0,1,0), (-s,0,c)
        R0 = c * Fc0 + s * Fc2;
        R1 = Fc1;
        R2 = c * Fc2 - s * Fc0;
    }
}

// fwd: computes this link's fl/fa (local frame) and updates v/a state in place.
// Constants staged as 6x float4 from LDS (ds_read_b128, proven r0 path).
template <int AX>
__device__ __forceinline__ void fwd_step(const float4* C4, float s, float c,
                                         float qd, float qdd, V3& vl, V3& va, V3& al,
                                         V3& aa, V3& fl, V3& fa) {
    const float4 A0 = C4[0], A1 = C4[1], A2 = C4[2], A3 = C4[3], A4 = C4[4], A5 = C4[5];
    const V3 Fc0{A0.x, A0.y, A0.z};
    const V3 Fc1{A0.w, A1.x, A1.y};
    const V3 Fc2{A1.z, A1.w, A2.x};
    const V3 p{A2.y, A2.z, A2.w};
    const float I00 = A3.x, I01 = A3.y, I02 = A3.z, I11 = A3.w, I12 = A4.x, I22 = A4.y;
    const float m = A4.z;
    const V3 mc{A4.w, A5.x, A5.y};

    V3 R0, R1, R2;
    make_R<AX>(Fc0, Fc1, Fc2, s, c, R0, R1, R2);

    // Rt(vl) + cross(-Rt p, Rt va) == Rt(vl + va x p)
    V3 w1 = vl + cross(va, p);
    V3 w2 = al + cross(aa, p);
    V3 nvl{dot(R0, w1), dot(R1, w1), dot(R2, w1)};
    V3 nva{dot(R0, va), dot(R1, va), dot(R2, va)};
    V3 nal{dot(R0, w2), dot(R1, w2), dot(R2, w2)};
    V3 naa{dot(R0, aa), dot(R1, aa), dot(R2, aa)};

    if (AX == 0) {          // jv=(0,0,qd): cross(v,jv)=(v.y*qd,-v.x*qd,0)
        va = {nva.x, nva.y, nva.z + qd};
        aa = {naa.x + va.y * qd, naa.y - va.x * qd, naa.z + qdd};
        vl = nvl;
        al = {nal.x + vl.y * qd, nal.y - vl.x * qd, nal.z};
    } else if (AX == 1) {   // jv=(0,qd,0): cross(v,jv)=(-v.z*qd,0,v.x*qd)
        va = {nva.x, nva.y + qd, nva.z};
        aa = {naa.x - va.z * qd, naa.y + qdd, naa.z + va.x * qd};
        vl = nvl;
        al = {nal.x - vl.z * qd, nal.y, nal.z + vl.x * qd};
    } else {                // jv=(0,-qd,0): cross(v,jv)=(v.z*qd,0,-v.x*qd)
        va = {nva.x, nva.y - qd, nva.z};
        aa = {naa.x + va.z * qd, naa.y - qdd, naa.z - va.x * qd};
        vl = nvl;
        al = {nal.x + vl.z * qd, nal.y, nal.z - vl.x * qd};
    }

    V3 Ial = m * al + cross(aa, mc);
    V3 Iaa = V3{I00 * aa.x + I01 * aa.y + I02 * aa.z,
                I01 * aa.x + I11 * aa.y + I12 * aa.z,
                I02 * aa.x + I12 * aa.y + I22 * aa.z} + cross(mc, al);
    V3 Ivl = m * vl + cross(va, mc);
    V3 Iva = V3{I00 * va.x + I01 * va.y + I02 * va.z,
                I01 * va.x + I11 * va.y + I12 * va.z,
                I02 * va.x + I12 * va.y + I22 * va.z} + cross(mc, vl);
    fl = Ial + cross(va, Ivl);
    fa = Iaa + cross(va, Iva) + cross(vl, Ivl);
}

// bwd: consumes fl/fa by value (LDS-parked), updates carry, returns tau.
template <int AX>
__device__ __forceinline__ float bwd_core(const float4* C4, float s, float c,
                                          V3 fl, V3 fa, V3& cl, V3& ca) {
    const float4 A0 = C4[0], A1 = C4[1], A2 = C4[2];   // only F and p needed
    const V3 Fc0{A0.x, A0.y, A0.z};
    const V3 Fc1{A0.w, A1.x, A1.y};
    const V3 Fc2{A1.z, A1.w, A2.x};
    const V3 p{A2.y, A2.z, A2.w};

    V3 tl = fl + cl;
    V3 ta = fa + ca;
    float tau;
    if (AX == 0) tau = ta.z;
    else if (AX == 1) tau = ta.y;
    else tau = -ta.y;

    V3 R0, R1, R2;
    make_R<AX>(Fc0, Fc1, Fc2, s, c, R0, R1, R2);
    V3 nl = tl.x * R0 + tl.y * R1 + tl.z * R2;   // R @ tl (columns)
    V3 na = ta.x * R0 + ta.y * R1 + ta.z * R2 + cross(p, nl);
    cl = nl;
    ca = na;
    return tau;
}

// axis id for dof d: sequence z,y,z,-y,z,y,z -> 0,1,0,2,0,1,0
__device__ __forceinline__ int axid(int d) { return (d & 1) ? ((d == 3) ? 2 : 1) : 0; }

// ---------- main kernel ----------
// LOOP-FORM O(n) two-pass RNEA.  Round 0-4 data fits dur ~ static_code x
// waves (r3: 2x code x 1/2 waves = unchanged; r1: 1.6x code = 1.6x dur;
// r4: +25% code = +18% dur), i.e. the giant straight-line bodies are
// front-end (I-fetch/issue) limited: each instruction fetched once per
// wave, no I$ reuse, VALUBusy pinned at 49% and insensitive to ILP.
// Fix: genuine loops (unroll disabled) with a wave-uniform switch on the
// axis id -> hot body ~4-5 KB, fully I$-resident after iteration 1.
//  - fl/fa parked in LDS [link][comp][thread]: lane-stride 1, conflict-free
//    (runtime-indexed array cannot live in registers; LDS avoids scratch).
//  - constants in LDS float4 (r0-proven; NOT s_load - r2 showed 112 SGPRs
//    can't hold 168 consts -> reload stalls).
//  - q/qd/qdd software-pipelined one iteration ahead; bwd reloads are L1-hot.
//  - tau stored straight from the bwd loop; no indexed tau array.
//  - prep inlined per block (r1-validated), removing the separate launch.
__global__ __launch_bounds__(BLK) void rnea_main(
    const float* __restrict__ q_g, const float* __restrict__ qd_g,
    const float* __restrict__ qdd_g,
    const float* __restrict__ rot_fix, const float* __restrict__ trans_fix,
    const float* __restrict__ mass_g, const float* __restrict__ com_g,
    const float* __restrict__ inertia_g, const float* __restrict__ damping_g,
    float* __restrict__ out, int nbatch) {
    __shared__ __align__(16) float sC[CST_TOT];
    __shared__ float sF[SF_FLOATS];
    const int t = threadIdx.x;
    const int row = blockIdx.x * BLK + t;
    const bool ok = row < nbatch;
    const int rc = ok ? row : (nbatch - 1);   // clamp: branch-free loads
    const size_t go = (size_t)rc * NDOF;

    // inline prep (7 threads; sources tiny + L2-resident)
    if (t < NDOF) {
        const int d = t;
        float* o = sC + d * CST_STRIDE;
        const float* F = rot_fix + (1 + d) * 9;
#pragma unroll
        for (int j = 0; j < 3; j++)
#pragma unroll
            for (int i = 0; i < 3; i++) o[j * 3 + i] = F[i * 3 + j];  // column-major
#pragma unroll
        for (int i = 0; i < 3; i++) o[9 + i] = trans_fix[(1 + d) * 3 + i];
        const float m = mass_g[1 + d];
        const float c0 = com_g[(1 + d) * 3 + 0];
        const float c1 = com_g[(1 + d) * 3 + 1];
        const float c2 = com_g[(1 + d) * 3 + 2];
        const float* I = inertia_g + (1 + d) * 9;
        o[12] = I[0] + m * (c1 * c1 + c2 * c2);
        o[13] = I[1] - m * c0 * c1;
        o[14] = I[2] - m * c0 * c2;
        o[15] = I[4] + m * (c0 * c0 + c2 * c2);
        o[16] = I[5] - m * c1 * c2;
        o[17] = I[8] + m * (c0 * c0 + c1 * c1);
        o[18] = m;
        o[19] = m * c0;
        o[20] = m * c1;
        o[21] = m * c2;
        o[22] = damping_g[d];
        o[23] = 0.f;
    }
    __syncthreads();

    // ---------------- forward pass (loop) ----------------
    V3 vl{0.f, 0.f, 0.f}, va{0.f, 0.f, 0.f}, al{0.f, 0.f, 9.81f}, aa{0.f, 0.f, 0.f};
    float q_n = q_g[go], qd_n = qd_g[go], qdd_n = qdd_g[go];
#pragma clang loop unroll(disable)
    for (int d = 0; d < NDOF; ++d) {
        const float qc = q_n, qdc = qd_n, qddc = qdd_n;
        const int dn = (d < NDOF - 1) ? (d + 1) : (NDOF - 1);
        q_n = q_g[go + dn];     // prefetch next iteration (hidden under compute)
        qd_n = qd_g[go + dn];
        qdd_n = qdd_g[go + dn];
        const float s = __sinf(qc), c = __cosf(qc);
        const float4* C4 = reinterpret_cast<const float4*>(sC) + d * 6;
        V3 fl, fa;
        switch (axid(d)) {
            case 0: fwd_step<0>(C4, s, c, qdc, qddc, vl, va, al, aa, fl, fa); break;
            case 1: fwd_step<1>(C4, s, c, qdc, qddc, vl, va, al, aa, fl, fa); break;
            default: fwd_step<2>(C4, s, c, qdc, qddc, vl, va, al, aa, fl, fa); break;
        }
        float* r = sF + d * 6 * BLK + t;   // [link][comp][thread]: conflict-free
        r[0 * BLK] = fl.x; r[1 * BLK] = fl.y; r[2 * BLK] = fl.z;
        r[3 * BLK] = fa.x; r[4 * BLK] = fa.y; r[5 * BLK] = fa.z;
    }

    // ---------------- backward pass (loop) ----------------
    // same-thread LDS reuse only -> no barrier needed between passes
    V3 cl{0.f, 0.f, 0.f}, ca{0.f, 0.f, 0.f};
#pragma clang loop unroll(disable)
    for (int d = NDOF - 1; d >= 0; --d) {
        const float qc = q_g[go + d];      // L1-hot reload
        const float qdc = qd_g[go + d];
        const float s = __sinf(qc), c = __cosf(qc);
        const float4* C4 = reinterpret_cast<const float4*>(sC) + d * 6;
        const float* r = sF + d * 6 * BLK + t;
        const V3 fl{r[0 * BLK], r[1 * BLK], r[2 * BLK]};
        const V3 fa{r[3 * BLK], r[4 * BLK], r[5 * BLK]};
        float tau;
        switch (axid(d)) {
            case 0: tau = bwd_core<0>(C4, s, c, fl, fa, cl, ca); break;
            case 1: tau = bwd_core<1>(C4, s, c, fl, fa, cl, ca); break;
            default: tau = bwd_core<2>(C4, s, c, fl, fa, cl, ca); break;
        }
        if (ok) out[go + d] = tau + sC[d * CST_STRIDE + 22] * qdc;
    }
}

extern "C" void kernel_launch(void* const* d_in, const int* in_sizes, int n_in,
                              void* d_out, int out_size, void* d_ws, size_t ws_size,
                              hipStream_t stream) {
    const float* q = (const float*)d_in[0];
    const float* qd = (const float*)d_in[1];
    const float* qdd = (const float*)d_in[2];
    const float* rot_fix = (const float*)d_in[3];
    const float* trans_fix = (const float*)d_in[4];
    // d_in[5] = joint_axes: compile-time constant in the reference (z,y,z,-y,z,y,z)
    const float* mass = (const float*)d_in[6];
    const float* com = (const float*)d_in[7];
    const float* inertia = (const float*)d_in[8];
    const float* damping = (const float*)d_in[9];
    float* out = (float*)d_out;

    const int n_elem = in_sizes[0];  // B * 7
    const int B = n_elem / NDOF;
    const int grid = (B + BLK - 1) / BLK;

    rnea_main<<<grid, BLK, 0, stream>>>(q, qd, qdd, rot_fix, trans_fix, mass, com,
                                        inertia, damping, out, B);
}

// Round 6
// 125.554 us; speedup vs baseline: 1.1229x; 1.0097x over previous
//
#include <hip/hip_runtime.h>

#define NDOF 7
#define NPARK 5                     // links 0..4 parked in LDS; 5,6 fused in regs
#define BLK 256
#define CST_STRIDE 24               // floats per dof block (= 6 float4)
#define CST_TOT (NDOF * CST_STRIDE) // 168
#define SF_FLOATS (NPARK * 6 * BLK) // 7680 floats = 30720 B parked wrenches

// ---------- tiny vec3 ----------
struct V3 { float x, y, z; };
__device__ __forceinline__ V3 operator+(V3 a, V3 b) { return {a.x + b.x, a.y + b.y, a.z + b.z}; }
__device__ __forceinline__ V3 operator-(V3 a, V3 b) { return {a.x - b.x, a.y - b.y, a.z - b.z}; }
__device__ __forceinline__ V3 operator*(float s, V3 a) { return {s * a.x, s * a.y, s * a.z}; }
__device__ __forceinline__ V3 cross(V3 a, V3 b) {
    return {a.y * b.z - a.z * b.y, a.z * b.x - a.x * b.z, a.x * b.y - a.y * b.x};
}
__device__ __forceinline__ float dot(V3 a, V3 b) { return a.x * b.x + a.y * b.y + a.z * b.z; }

// AX: 0 = +z, 1 = +y, 2 = -y   (joint_axes is a literal in the reference)
template <int AX>
__device__ __forceinline__ void make_R(V3 Fc0, V3 Fc1, V3 Fc2, float s, float c,
                                       V3& R0, V3& R1, V3& R2) {
    if (AX == 0) {          // Rq_z cols: (c,s,0), (-s,c,0), (0,0,1)
        R0 = c * Fc0 + s * Fc1;
        R1 = c * Fc1 - s * Fc0;
        R2 = Fc2;
    } else if (AX == 1) {   // Rq_y cols: (c,0,-s), (0,1,0), (s,0,c)
        R0 = c * Fc0 - s * Fc2;
        R1 = Fc1;
        R2 = s * Fc0 + c * Fc2;
    } else {                // Rq_-y cols: (c,0,s), (0,1,0), (-s,0,c)
        R0 = c * Fc0 + s * Fc2;
        R1 = Fc1;
        R2 = c * Fc2 - s * Fc0;
    }
}

// fwd: computes this link's fl/fa (local frame) and updates v/a state in place.
// Constants staged as 6x float4 from LDS (ds_read_b128).
template <int AX>
__device__ __forceinline__ void fwd_step(const float4* C4, float s, float c,
                                         float qd, float qdd, V3& vl, V3& va, V3& al,
                                         V3& aa, V3& fl, V3& fa) {
    const float4 A0 = C4[0], A1 = C4[1], A2 = C4[2], A3 = C4[3], A4 = C4[4], A5 = C4[5];
    const V3 Fc0{A0.x, A0.y, A0.z};
    const V3 Fc1{A0.w, A1.x, A1.y};
    const V3 Fc2{A1.z, A1.w, A2.x};
    const V3 p{A2.y, A2.z, A2.w};
    const float I00 = A3.x, I01 = A3.y, I02 = A3.z, I11 = A3.w, I12 = A4.x, I22 = A4.y;
    const float m = A4.z;
    const V3 mc{A4.w, A5.x, A5.y};

    V3 R0, R1, R2;
    make_R<AX>(Fc0, Fc1, Fc2, s, c, R0, R1, R2);

    // Rt(vl) + cross(-Rt p, Rt va) == Rt(vl + va x p)
    V3 w1 = vl + cross(va, p);
    V3 w2 = al + cross(aa, p);
    V3 nvl{dot(R0, w1), dot(R1, w1), dot(R2, w1)};
    V3 nva{dot(R0, va), dot(R1, va), dot(R2, va)};
    V3 nal{dot(R0, w2), dot(R1, w2), dot(R2, w2)};
    V3 naa{dot(R0, aa), dot(R1, aa), dot(R2, aa)};

    if (AX == 0) {          // jv=(0,0,qd): cross(v,jv)=(v.y*qd,-v.x*qd,0)
        va = {nva.x, nva.y, nva.z + qd};
        aa = {naa.x + va.y * qd, naa.y - va.x * qd, naa.z + qdd};
        vl = nvl;
        al = {nal.x + vl.y * qd, nal.y - vl.x * qd, nal.z};
    } else if (AX == 1) {   // jv=(0,qd,0): cross(v,jv)=(-v.z*qd,0,v.x*qd)
        va = {nva.x, nva.y + qd, nva.z};
        aa = {naa.x - va.z * qd, naa.y + qdd, naa.z + va.x * qd};
        vl = nvl;
        al = {nal.x - vl.z * qd, nal.y, nal.z + vl.x * qd};
    } else {                // jv=(0,-qd,0): cross(v,jv)=(v.z*qd,0,-v.x*qd)
        va = {nva.x, nva.y - qd, nva.z};
        aa = {naa.x + va.z * qd, naa.y - qdd, naa.z - va.x * qd};
        vl = nvl;
        al = {nal.x + vl.z * qd, nal.y, nal.z - vl.x * qd};
    }

    V3 Ial = m * al + cross(aa, mc);
    V3 Iaa = V3{I00 * aa.x + I01 * aa.y + I02 * aa.z,
                I01 * aa.x + I11 * aa.y + I12 * aa.z,
                I02 * aa.x + I12 * aa.y + I22 * aa.z} + cross(mc, al);
    V3 Ivl = m * vl + cross(va, mc);
    V3 Iva = V3{I00 * va.x + I01 * va.y + I02 * va.z,
                I01 * va.x + I11 * va.y + I12 * va.z,
                I02 * va.x + I12 * va.y + I22 * va.z} + cross(mc, vl);
    fl = Ial + cross(va, Ivl);
    fa = Iaa + cross(va, Iva) + cross(vl, Ivl);
}

// bwd: consumes fl/fa by value, updates carry, returns tau.
template <int AX>
__device__ __forceinline__ float bwd_core(const float4* C4, float s, float c,
                                          V3 fl, V3 fa, V3& cl, V3& ca) {
    const float4 A0 = C4[0], A1 = C4[1], A2 = C4[2];   // only F and p needed
    const V3 Fc0{A0.x, A0.y, A0.z};
    const V3 Fc1{A0.w, A1.x, A1.y};
    const V3 Fc2{A1.z, A1.w, A2.x};
    const V3 p{A2.y, A2.z, A2.w};

    V3 tl = fl + cl;
    V3 ta = fa + ca;
    float tau;
    if (AX == 0) tau = ta.z;
    else if (AX == 1) tau = ta.y;
    else tau = -ta.y;

    V3 R0, R1, R2;
    make_R<AX>(Fc0, Fc1, Fc2, s, c, R0, R1, R2);
    V3 nl = tl.x * R0 + tl.y * R1 + tl.z * R2;   // R @ tl (columns)
    V3 na = ta.x * R0 + ta.y * R1 + ta.z * R2 + cross(p, nl);
    cl = nl;
    ca = na;
    return tau;
}

// axis id for dof d: sequence z,y,z,-y,z,y,z -> 0,1,0,2,0,1,0
__device__ __forceinline__ int axid(int d) { return (d & 1) ? ((d == 3) ? 2 : 1) : 0; }

// ---------- main kernel ----------
// Loop-form O(n) RNEA (r5) + occupancy unlock + store fix:
//  - r5 counters: VALUBusy 57% @ 24.6% occupancy, LDS-capped at 3 blocks/CU
//    (44 KB sF).  Peeling links 5,6 into registers (produced last in fwd,
//    consumed first in bwd -> zero extra liveness) shrinks sF to 30.7 KB ->
//    5 blocks/CU = 20 waves/CU ceiling.
//  - r5 regression: WRITE_SIZE 14.3->19.4 MB because output stores were
//    spread across bwd iterations (partial-line eviction).  Fix: park each
//    finished tau in the just-freed sF slot (same-thread, no barrier) and
//    issue all 7 global stores back-to-back at the end.
//  - no forced occupancy cap (historical: caps trigger scratch spill).
__global__ __launch_bounds__(BLK) void rnea_main(
    const float* __restrict__ q_g, const float* __restrict__ qd_g,
    const float* __restrict__ qdd_g,
    const float* __restrict__ rot_fix, const float* __restrict__ trans_fix,
    const float* __restrict__ mass_g, const float* __restrict__ com_g,
    const float* __restrict__ inertia_g, const float* __restrict__ damping_g,
    float* __restrict__ out, int nbatch) {
    __shared__ __align__(16) float sC[CST_TOT];
    __shared__ float sF[SF_FLOATS];
    const int t = threadIdx.x;
    const int row = blockIdx.x * BLK + t;
    const bool ok = row < nbatch;
    const int rc = ok ? row : (nbatch - 1);   // clamp: branch-free loads
    const size_t go = (size_t)rc * NDOF;

    // inline prep (7 threads; sources tiny + L2-resident)
    if (t < NDOF) {
        const int d = t;
        float* o = sC + d * CST_STRIDE;
        const float* F = rot_fix + (1 + d) * 9;
#pragma unroll
        for (int j = 0; j < 3; j++)
#pragma unroll
            for (int i = 0; i < 3; i++) o[j * 3 + i] = F[i * 3 + j];  // column-major
#pragma unroll
        for (int i = 0; i < 3; i++) o[9 + i] = trans_fix[(1 + d) * 3 + i];
        const float m = mass_g[1 + d];
        const float c0 = com_g[(1 + d) * 3 + 0];
        const float c1 = com_g[(1 + d) * 3 + 1];
        const float c2 = com_g[(1 + d) * 3 + 2];
        const float* I = inertia_g + (1 + d) * 9;
        o[12] = I[0] + m * (c1 * c1 + c2 * c2);
        o[13] = I[1] - m * c0 * c1;
        o[14] = I[2] - m * c0 * c2;
        o[15] = I[4] + m * (c0 * c0 + c2 * c2);
        o[16] = I[5] - m * c1 * c2;
        o[17] = I[8] + m * (c0 * c0 + c1 * c1);
        o[18] = m;
        o[19] = m * c0;
        o[20] = m * c1;
        o[21] = m * c2;
        o[22] = damping_g[d];
        o[23] = 0.f;
    }
    __syncthreads();

    // ---------------- forward pass: loop over parked links 0..4 ----------------
    V3 vl{0.f, 0.f, 0.f}, va{0.f, 0.f, 0.f}, al{0.f, 0.f, 9.81f}, aa{0.f, 0.f, 0.f};
    float q_n = q_g[go], qd_n = qd_g[go], qdd_n = qdd_g[go];
#pragma clang loop unroll(disable)
    for (int d = 0; d < NPARK; ++d) {
        const float qc = q_n, qdc = qd_n, qddc = qdd_n;
        q_n = q_g[go + d + 1];     // prefetch next (d+1 <= 5; hidden under compute)
        qd_n = qd_g[go + d + 1];
        qdd_n = qdd_g[go + d + 1];
        const float s = __sinf(qc), c = __cosf(qc);
        const float4* C4 = reinterpret_cast<const float4*>(sC) + d * 6;
        V3 fl, fa;
        switch (axid(d)) {
            case 0: fwd_step<0>(C4, s, c, qdc, qddc, vl, va, al, aa, fl, fa); break;
            case 1: fwd_step<1>(C4, s, c, qdc, qddc, vl, va, al, aa, fl, fa); break;
            default: fwd_step<2>(C4, s, c, qdc, qddc, vl, va, al, aa, fl, fa); break;
        }
        float* r = sF + d * 6 * BLK + t;   // [link][comp][thread]: conflict-free
        r[0 * BLK] = fl.x; r[1 * BLK] = fl.y; r[2 * BLK] = fl.z;
        r[3 * BLK] = fa.x; r[4 * BLK] = fa.y; r[5 * BLK] = fa.z;
    }

    // ---------------- peel: links 5,6 fwd -> immediate bwd in registers ----------
    const float q5 = q_n, qd5 = qd_n, qdd5 = qdd_n;      // prefetched above
    const float q6 = q_g[go + 6], qd6 = qd_g[go + 6], qdd6 = qdd_g[go + 6];
    const float s5 = __sinf(q5), c5 = __cosf(q5);
    const float s6 = __sinf(q6), c6 = __cosf(q6);
    V3 fl5, fa5, fl6, fa6;
    fwd_step<1>(reinterpret_cast<const float4*>(sC) + 5 * 6, s5, c5, qd5, qdd5,
                vl, va, al, aa, fl5, fa5);
    fwd_step<0>(reinterpret_cast<const float4*>(sC) + 6 * 6, s6, c6, qd6, qdd6,
                vl, va, al, aa, fl6, fa6);

    V3 cl{0.f, 0.f, 0.f}, ca{0.f, 0.f, 0.f};
    const float tau6 = bwd_core<0>(reinterpret_cast<const float4*>(sC) + 6 * 6,
                                   s6, c6, fl6, fa6, cl, ca) +
                       sC[6 * CST_STRIDE + 22] * qd6;
    const float tau5 = bwd_core<1>(reinterpret_cast<const float4*>(sC) + 5 * 6,
                                   s5, c5, fl5, fa5, cl, ca) +
                       sC[5 * CST_STRIDE + 22] * qd5;

    // ---------------- backward pass: loop over parked links 4..0 ----------------
    // same-thread LDS reuse only -> no barrier; finished tau overwrites the
    // just-consumed fl.x slot so all global stores can issue together below.
#pragma clang loop unroll(disable)
    for (int d = NPARK - 1; d >= 0; --d) {
        const float qc = q_g[go + d];      // L1-hot reload
        const float qdc = qd_g[go + d];
        const float s = __sinf(qc), c = __cosf(qc);
        const float4* C4 = reinterpret_cast<const float4*>(sC) + d * 6;
        float* r = sF + d * 6 * BLK + t;
        const V3 fl{r[0 * BLK], r[1 * BLK], r[2 * BLK]};
        const V3 fa{r[3 * BLK], r[4 * BLK], r[5 * BLK]};
        float tau;
        switch (axid(d)) {
            case 0: tau = bwd_core<0>(C4, s, c, fl, fa, cl, ca); break;
            case 1: tau = bwd_core<1>(C4, s, c, fl, fa, cl, ca); break;
            default: tau = bwd_core<2>(C4, s, c, fl, fa, cl, ca); break;
        }
        r[0] = tau + sC[d * CST_STRIDE + 22] * qdc;   // park finished tau
    }

    // ---------------- stores: all 7 back-to-back (write-combine friendly) -------
    if (ok) {
#pragma unroll
        for (int d = 0; d < NPARK; ++d) out[go + d] = sF[d * 6 * BLK + t];
        out[go + 5] = tau5;
        out[go + 6] = tau6;
    }
}

extern "C" void kernel_launch(void* const* d_in, const int* in_sizes, int n_in,
                              void* d_out, int out_size, void* d_ws, size_t ws_size,
                              hipStream_t stream) {
    const float* q = (const float*)d_in[0];
    const float* qd = (const float*)d_in[1];
    const float* qdd = (const float*)d_in[2];
    const float* rot_fix = (const float*)d_in[3];
    const float* trans_fix = (const float*)d_in[4];
    // d_in[5] = joint_axes: compile-time constant in the reference (z,y,z,-y,z,y,z)
    const float* mass = (const float*)d_in[6];
    const float* com = (const float*)d_in[7];
    const float* inertia = (const float*)d_in[8];
    const float* damping = (const float*)d_in[9];
    float* out = (float*)d_out;

    const int n_elem = in_sizes[0];  // B * 7
    const int B = n_elem / NDOF;
    const int grid = (B + BLK - 1) / BLK;

    rnea_main<<<grid, BLK, 0, stream>>>(q, qd, qdd, rot_fix, trans_fix, mass, com,
                                        inertia, damping, out, B);
}